// Round 3
// baseline (137.761 us; speedup 1.0000x reference)
//
#include <hip/hip_runtime.h>
#include <hip/hip_cooperative_groups.h>

namespace cg = cooperative_groups;

#define BB 4
#define NTOK 2048
#define E 96
#define NH 6
#define DH 16
#define E3 288
#define GSZ (E*E)          // 9216
#define PART (GSZ + E)     // 9312 floats per partial block (G + s); also 97*96 (Wc)
#define NSPLIT 32
#define SCALE 0.25f        // D^-0.5 = 1/sqrt(16)

__global__ __launch_bounds__(256) void k_fused(const float* __restrict__ x,
                                               const float* __restrict__ Wqkv,
                                               const float* __restrict__ bqkv,
                                               const float* __restrict__ Wff,
                                               const float* __restrict__ bff,
                                               float* __restrict__ out,
                                               float* __restrict__ gpart,
                                               float* __restrict__ P,
                                               float* __restrict__ ss_g,
                                               float* __restrict__ Wc) {
    cg::grid_group grid = cg::this_grid();
    __shared__ float4 sm4[3225];             // 51.6 KB, re-partitioned per phase
    float* sm = (float*)sm4;
    const int t = threadIdx.x;
    const int blk = blockIdx.x;

    // ================= P1: G partials + s partials (blocks 0..127) ==========
    if (blk < BB * NSPLIT) {
        const int b = blk >> 5, sp = blk & 31;
        const int n0 = sp * (NTOK / NSPLIT);     // 64 rows
        float4* xs4 = sm4;
        float* xs = sm;                          // 64 rows x 100-float stride
        const int te1 = (t >> 4) * 6, te2 = (t & 15) * 6;

        const float4* x4 = (const float4*)(x + ((size_t)b * NTOK + n0) * E);
#pragma unroll
        for (int i = 0; i < 6; i++) {            // 64*24 = 1536 float4
            int f = t + i * 256;
            xs4[(f / 24) * 25 + (f % 24)] = x4[f];
        }
        __syncthreads();

        float acc[36];
#pragma unroll
        for (int i = 0; i < 36; i++) acc[i] = 0.f;
        for (int n = 0; n < 64; n++) {
            float a[6], c[6];
#pragma unroll
            for (int j = 0; j < 6; j++) { a[j] = xs[n * 100 + te1 + j]; c[j] = xs[n * 100 + te2 + j]; }
#pragma unroll
            for (int ii = 0; ii < 6; ii++)
#pragma unroll
                for (int jj = 0; jj < 6; jj++)
                    acc[ii * 6 + jj] += a[ii] * c[jj];
        }
        float* gp = gpart + (size_t)blk * PART;
#pragma unroll
        for (int ii = 0; ii < 6; ii++)
#pragma unroll
            for (int jj = 0; jj < 6; jj++)
                gp[(te1 + ii) * E + te2 + jj] = acc[ii * 6 + jj];
        if (t < E) {
            float sacc = 0.f;
            for (int n = 0; n < 64; n++) sacc += xs[n * 100 + t];
            gp[GSZ + t] = sacc;
        }
    }
    grid.sync();

    // ===== P2: reduce G (4 rows/block) + P = Grows@Wv; s-reduce; Wc zero ====
    if (blk < BB * 24) {
        const int b = blk / 24, rg = blk % 24;
        const int r0 = rg * 4;
        float* Gs = sm;                          // 4 x 96

        if (t < 96) {
            const float4* gp4 = (const float4*)(gpart + (size_t)b * NSPLIT * PART);
            float4 a = make_float4(0.f, 0.f, 0.f, 0.f);
            const float4* p = gp4 + r0 * 24 + t;
#pragma unroll
            for (int sp = 0; sp < NSPLIT; sp++) {    // 32 independent b128 loads
                float4 g = p[(size_t)sp * (PART / 4)];
                a.x += g.x; a.y += g.y; a.z += g.z; a.w += g.w;
            }
            ((float4*)Gs)[t] = a;
        } else if (rg == 0 && t < 192) {             // s reduce (once per batch)
            const int j = t - 96;
            float v = 0.f;
            const float* gp = gpart + (size_t)b * NSPLIT * PART + GSZ + j;
#pragma unroll
            for (int sp = 0; sp < NSPLIT; sp++) v += gp[(size_t)sp * PART];
            ss_g[b * E + j] = v;
        } else if (rg == 1) {                        // zero Wc (once per batch)
            for (int i = t - 96; i < PART; i += 160) Wc[(size_t)b * PART + i] = 0.f;
        }
        __syncthreads();

        // P rows: 4 x 96 outputs
        for (int f = t; f < 384; f += 256) {
            const int r = f / 96, c = f % 96;
            float v = 0.f;
            for (int e = 0; e < E; e++) v += Gs[r * 96 + e] * Wqkv[e * E3 + 2 * E + c];
            P[(size_t)b * GSZ + (r0 + r) * E + c] = v;
        }
    }
    grid.sync();

    // ========= P3: per (b,h): M_h -> U_h -> Wc += Wq_h @ U_h (atomic) =======
    if (blk < BB * NH) {
        const int b = blk / NH, h = blk % NH;
        float* Ph  = sm;               // 96 x 16
        float* ssL = sm + 1536;        // 96
        float* skk = sm + 1632;        // 16
        float* svv = sm + 1648;        // 16
        float* Ms  = sm + 1664;        // 256
        float* rr  = sm + 1920;        // 16
        float* U   = sm + 1936;        // 16 x 96

        {
            const float4* P4r = (const float4*)(P + (size_t)b * GSZ + h * DH);
            float4* Ph4 = (float4*)Ph;
            for (int f = t; f < 384; f += 256) {
                const int e = f >> 2, q = f & 3;
                Ph4[f] = P4r[e * 24 + q];
            }
            if (t < E) ssL[t] = ss_g[b * E + t];
        }
        __syncthreads();
        if (t < 2 * DH) {
            const int d = t & 15;
            const int col = (t < DH) ? (E + h * DH + d) : (2 * E + h * DH + d);
            float v = 0.f;
            for (int e = 0; e < E; e++) v += ssL[e] * Wqkv[e * E3 + col];
            if (t < DH) skk[d] = v; else svv[d] = v;
        }
        __syncthreads();
        {
            const int d1 = t >> 4, d2 = t & 15;
            const int j1 = h * DH + d1;
            float v = 0.f;
            for (int e = 0; e < E; e++) v += Wqkv[e * E3 + E + j1] * Ph[e * DH + d2];
            const float bk = bqkv[E + j1], bv = bqkv[2 * E + h * DH + d2];
            v += bk * svv[d2] + skk[d1] * bv + (float)NTOK * bk * bv;
            Ms[t] = SCALE * v;
        }
        __syncthreads();
        if (t < DH) {
            float v = 0.f;
#pragma unroll
            for (int d1 = 0; d1 < DH; d1++) v += bqkv[h * DH + d1] * Ms[d1 * DH + t];
            rr[t] = v;
        }
        {
            const int d1 = t >> 4, eb = (t & 15) * 6;
            float acc[6] = {0.f, 0.f, 0.f, 0.f, 0.f, 0.f};
#pragma unroll
            for (int d2 = 0; d2 < DH; d2++) {
                const float m = Ms[d1 * DH + d2];
                const float* w = &Wff[(h * DH + d2) * E + eb];
#pragma unroll
                for (int j = 0; j < 6; j++) acc[j] += m * w[j];
            }
#pragma unroll
            for (int j = 0; j < 6; j++) U[d1 * E + eb + j] = acc[j];
        }
        __syncthreads();
        // Wc[r][c] += sum_d Wq[r][h*16+d] * U[d][c]   (96x96 per head)
        {
            const int r6 = (t >> 4) * 6, c6 = (t & 15) * 6;
            float acc[36];
#pragma unroll
            for (int i = 0; i < 36; i++) acc[i] = 0.f;
#pragma unroll
            for (int d = 0; d < DH; d++) {
                float wq[6], u[6];
#pragma unroll
                for (int i = 0; i < 6; i++) wq[i] = Wqkv[(r6 + i) * E3 + h * DH + d];
#pragma unroll
                for (int j = 0; j < 6; j++) u[j] = U[d * E + c6 + j];
#pragma unroll
                for (int i = 0; i < 6; i++)
#pragma unroll
                    for (int j = 0; j < 6; j++)
                        acc[i * 6 + j] += wq[i] * u[j];
            }
#pragma unroll
            for (int i = 0; i < 6; i++)
#pragma unroll
                for (int j = 0; j < 6; j++)
                    atomicAdd(&Wc[(size_t)b * PART + (r6 + i) * E + c6 + j], acc[i * 6 + j]);
        }
        if (t < E) {                 // bias row (row 96)
            float v = (h == 0) ? bff[t] : 0.f;
#pragma unroll
            for (int d = 0; d < DH; d++) v += rr[d] * Wff[(h * DH + d) * E + t];
            atomicAdd(&Wc[(size_t)b * PART + GSZ + t], v);
        }
    }
    grid.sync();

    // ================= P4: out[b] = x[b] @ Wc[b] + bias row (all 256) =======
    {
        const int b = blk >> 6, tile = blk & 63;
        const int n0 = tile * 32;
        float4* xs4 = sm4;                       // 32 x 25 float4
        float4* wcs4 = sm4 + 800;                // 97 x 25 float4
        float* xs = (float*)xs4;
        float* wcs = (float*)wcs4;

        const float4* x4 = (const float4*)(x + ((size_t)b * NTOK + n0) * E);
#pragma unroll
        for (int i = 0; i < 3; i++) {
            int f = t + i * 256;
            xs4[(f / 24) * 25 + (f % 24)] = x4[f];
        }
        const float4* w4 = (const float4*)(Wc + (size_t)b * PART);
#pragma unroll
        for (int i = 0; i < 10; i++) {
            int f = t + i * 256;
            if (f < 2328) wcs4[(f / 24) * 25 + (f % 24)] = w4[f];
        }
        __syncthreads();

        const int r = t >> 3;
        const int c4 = (t & 7) * 3;
        float acc[12];
#pragma unroll
        for (int j = 0; j < 12; j++) acc[j] = wcs[96 * 100 + c4 * 4 + j];
        for (int k = 0; k < E; k++) {
            const float xr = xs[r * 100 + k];
            const float4 w0 = wcs4[k * 25 + c4];
            const float4 w1 = wcs4[k * 25 + c4 + 1];
            const float4 w2 = wcs4[k * 25 + c4 + 2];
            acc[0] += xr * w0.x; acc[1] += xr * w0.y; acc[2]  += xr * w0.z; acc[3]  += xr * w0.w;
            acc[4] += xr * w1.x; acc[5] += xr * w1.y; acc[6]  += xr * w1.z; acc[7]  += xr * w1.w;
            acc[8] += xr * w2.x; acc[9] += xr * w2.y; acc[10] += xr * w2.z; acc[11] += xr * w2.w;
        }
        float4* o4 = (float4*)(out + ((size_t)(b * NTOK + n0 + r)) * E + c4 * 4);
        o4[0] = make_float4(acc[0], acc[1], acc[2], acc[3]);
        o4[1] = make_float4(acc[4], acc[5], acc[6], acc[7]);
        o4[2] = make_float4(acc[8], acc[9], acc[10], acc[11]);
    }
}

extern "C" void kernel_launch(void* const* d_in, const int* in_sizes, int n_in,
                              void* d_out, int out_size, void* d_ws, size_t ws_size,
                              hipStream_t stream) {
    const float* x    = (const float*)d_in[0];
    const float* Wqkv = (const float*)d_in[1];
    const float* bqkv = (const float*)d_in[2];
    const float* Wff  = (const float*)d_in[3];
    const float* bff  = (const float*)d_in[4];
    float* out = (float*)d_out;
    float* ws  = (float*)d_ws;

    float* gpart = ws;                                   // BB*NSPLIT*PART
    float* P     = ws + (size_t)BB * NSPLIT * PART;      // BB*GSZ
    float* ss_g  = P + (size_t)BB * GSZ;                 // BB*E (16B-aligned: 384 floats)
    float* Wc    = ss_g + (size_t)BB * E;                // BB*PART

    void* args[] = { (void*)&x, (void*)&Wqkv, (void*)&bqkv, (void*)&Wff, (void*)&bff,
                     (void*)&out, (void*)&gpart, (void*)&P, (void*)&ss_g, (void*)&Wc };
    hipLaunchCooperativeKernel((void*)k_fused, dim3(256), dim3(256), args, 0, stream);
}

// Round 4
// 31.225 us; speedup vs baseline: 4.4118x; 4.4118x over previous
//
#include <hip/hip_runtime.h>

#define BB 4
#define NTOK 2048
#define E 96
#define NH 6
#define DH 16
#define E3 288
#define MSZ (NH*DH*DH)     // 1536 floats per batch
#define SCALE 0.25f        // D^-0.5 = 1/sqrt(16)

// ---- K1: per 32-row tile: KV = x@[Wk|Wv]+bias (LDS), partial M_h = K_h^T V_h,
// ----     unsafeAtomicAdd into Mg[b] (6 KB per batch)
__global__ __launch_bounds__(256) void k_kv(const float* __restrict__ x,
                                            const float* __restrict__ Wqkv,
                                            const float* __restrict__ bqkv,
                                            float* __restrict__ Mg) {
    const int b = blockIdx.x >> 6, tile = blockIdx.x & 63;
    const int n0 = tile * 32;
    const int t = threadIdx.x;
    __shared__ float xs[32 * 100];       // x tile, f4 stride 25
    __shared__ float wkv[96 * 196];      // [Wk|Wv] 96x192, f4 stride 49
    __shared__ float kv[32 * 196];       // KV tile 32x192, f4 stride 49

    { // stage x: 768 float4
        const float4* src = (const float4*)(x + ((size_t)b * NTOK + n0) * E);
        float4* dst = (float4*)xs;
#pragma unroll
        for (int i = 0; i < 3; i++) {
            int f = t + i * 256;
            dst[(f / 24) * 25 + (f % 24)] = src[f];
        }
    }
    { // stage Wkv: 4608 float4 (cols 96..287 of Wqkv)
        const float4* src = (const float4*)Wqkv;
        float4* dst = (float4*)wkv;
#pragma unroll
        for (int i = 0; i < 18; i++) {
            int f = t + i * 256;
            int e = f / 48, c4 = f % 48;
            dst[e * 49 + c4] = src[e * 72 + 24 + c4];
        }
    }
    __syncthreads();

    { // KV compute: rows 2*(t>>4)+i, cols (t&15)*12+j ; 2304 FMA/thread
        const int r0 = (t >> 4) * 2;
        const int c0 = (t & 15) * 12;
        float acc[2][12];
#pragma unroll
        for (int i = 0; i < 2; i++)
#pragma unroll
            for (int j = 0; j < 12; j++) acc[i][j] = bqkv[E + c0 + j];
        for (int e = 0; e < E; e++) {
            float w[12], xv0, xv1;
#pragma unroll
            for (int j = 0; j < 12; j++) w[j] = wkv[e * 196 + c0 + j];
            xv0 = xs[r0 * 100 + e];
            xv1 = xs[(r0 + 1) * 100 + e];
#pragma unroll
            for (int j = 0; j < 12; j++) acc[0][j] += xv0 * w[j];
#pragma unroll
            for (int j = 0; j < 12; j++) acc[1][j] += xv1 * w[j];
        }
#pragma unroll
        for (int i = 0; i < 2; i++)
#pragma unroll
            for (int j = 0; j < 12; j++) kv[(r0 + i) * 196 + c0 + j] = acc[i][j];
    }
    __syncthreads();

    { // partial M: thread owns (d1,d2) for all 6 heads; 6 atomics/thread
        const int d1 = t >> 4, d2 = t & 15;
        float m[NH] = {0.f, 0.f, 0.f, 0.f, 0.f, 0.f};
        for (int n = 0; n < 32; n++) {
            const float* row = &kv[n * 196];
#pragma unroll
            for (int h = 0; h < NH; h++)
                m[h] += row[h * 16 + d1] * row[96 + h * 16 + d2];
        }
#pragma unroll
        for (int h = 0; h < NH; h++)
            unsafeAtomicAdd(&Mg[b * MSZ + h * 256 + d1 * 16 + d2], m[h]);
    }
}

// ---- K2: per 32-row tile: q = x@Wq+bq, t2 = q.BD(SCALE*M), out = t2@Wff+bff
__global__ __launch_bounds__(256) void k_out(const float* __restrict__ x,
                                             const float* __restrict__ Wqkv,
                                             const float* __restrict__ bqkv,
                                             const float* __restrict__ Wff,
                                             const float* __restrict__ bff,
                                             const float* __restrict__ Mg,
                                             float* __restrict__ out) {
    const int b = blockIdx.x >> 6, tile = blockIdx.x & 63;
    const int n0 = tile * 32;
    const int t = threadIdx.x;
    __shared__ float xs[32 * 100];       // f4 stride 25
    __shared__ float wbuf[96 * 100];     // Wq, then Wff
    __shared__ float Ms[NH * DH * 17];   // h*272 + d1*17 + d2 (pad 17)
    __shared__ float qs[32 * 100];
    __shared__ float t2[32 * 100];

    { // stage x
        const float4* src = (const float4*)(x + ((size_t)b * NTOK + n0) * E);
        float4* dst = (float4*)xs;
#pragma unroll
        for (int i = 0; i < 3; i++) {
            int f = t + i * 256;
            dst[(f / 24) * 25 + (f % 24)] = src[f];
        }
    }
    { // stage Wq (cols 0..95 of Wqkv): 2304 float4
        const float4* src = (const float4*)Wqkv;
        float4* dst = (float4*)wbuf;
#pragma unroll
        for (int i = 0; i < 9; i++) {
            int f = t + i * 256;
            int e = f / 24, c4 = f % 24;
            dst[e * 25 + c4] = src[e * 72 + c4];
        }
    }
    { // stage M (scaled)
#pragma unroll
        for (int i = 0; i < 6; i++) {
            int o = t + i * 256;
            int h = o >> 8, d1 = (o >> 4) & 15, d2 = o & 15;
            Ms[h * 272 + d1 * 17 + d2] = SCALE * Mg[b * MSZ + o];
        }
    }
    __syncthreads();

    const int r = t >> 3, c0 = (t & 7) * 12;   // 32 rows x (8 groups x 12 cols)
    { // q = x@Wq + bq  (1152 FMA)
        float acc[12];
#pragma unroll
        for (int j = 0; j < 12; j++) acc[j] = bqkv[c0 + j];
        for (int e = 0; e < E; e++) {
            float xv = xs[r * 100 + e];
#pragma unroll
            for (int j = 0; j < 12; j++) acc[j] += xv * wbuf[e * 100 + c0 + j];
        }
#pragma unroll
        for (int j = 0; j < 12; j++) qs[r * 100 + c0 + j] = acc[j];
    }
    __syncthreads();
    { // restage wbuf <- Wff (rows 96x96)
        const float4* src = (const float4*)Wff;
        float4* dst = (float4*)wbuf;
#pragma unroll
        for (int i = 0; i < 9; i++) {
            int f = t + i * 256;
            int e = f / 24, c4 = f % 24;
            dst[e * 25 + c4] = src[e * 24 + c4];
        }
    }
    { // t2 = q . BD(Ms)  (192 FMA)
        float acc[12];
#pragma unroll
        for (int j = 0; j < 12; j++) {
            const int c = c0 + j, h = c >> 4, d2 = c & 15;
            float v = 0.f;
#pragma unroll
            for (int d1 = 0; d1 < DH; d1++)
                v += qs[r * 100 + h * 16 + d1] * Ms[h * 272 + d1 * 17 + d2];
            acc[j] = v;
        }
#pragma unroll
        for (int j = 0; j < 12; j++) t2[r * 100 + c0 + j] = acc[j];
    }
    __syncthreads();
    { // out = t2 @ Wff + bff  (1152 FMA), float4 stores
        float acc[12];
#pragma unroll
        for (int j = 0; j < 12; j++) acc[j] = bff[c0 + j];
        for (int e = 0; e < E; e++) {
            float tv = t2[r * 100 + e];
#pragma unroll
            for (int j = 0; j < 12; j++) acc[j] += tv * wbuf[e * 100 + c0 + j];
        }
        float4* o4 = (float4*)(out + ((size_t)b * NTOK + n0 + r) * E + c0);
        o4[0] = make_float4(acc[0], acc[1], acc[2], acc[3]);
        o4[1] = make_float4(acc[4], acc[5], acc[6], acc[7]);
        o4[2] = make_float4(acc[8], acc[9], acc[10], acc[11]);
    }
}

extern "C" void kernel_launch(void* const* d_in, const int* in_sizes, int n_in,
                              void* d_out, int out_size, void* d_ws, size_t ws_size,
                              hipStream_t stream) {
    const float* x    = (const float*)d_in[0];
    const float* Wqkv = (const float*)d_in[1];
    const float* bqkv = (const float*)d_in[2];
    const float* Wff  = (const float*)d_in[3];
    const float* bff  = (const float*)d_in[4];
    float* out = (float*)d_out;
    float* Mg  = (float*)d_ws;                     // BB * 1536 floats

    hipMemsetAsync(Mg, 0, (size_t)BB * MSZ * sizeof(float), stream);
    k_kv<<<BB * 64, 256, 0, stream>>>(x, Wqkv, bqkv, Mg);
    k_out<<<BB * 64, 256, 0, stream>>>(x, Wqkv, bqkv, Wff, bff, Mg, out);
}